// Round 5
// baseline (96.014 us; speedup 1.0000x reference)
//
#include <hip/hip_runtime.h>
#include <hip/hip_bf16.h>

typedef __attribute__((ext_vector_type(8))) short bf16x8;
typedef __attribute__((ext_vector_type(4))) short bf16x4;
typedef __attribute__((ext_vector_type(4))) float f32x4;
typedef __attribute__((ext_vector_type(4))) unsigned int u32x4;
typedef __attribute__((ext_vector_type(2))) unsigned int u32x2;

#define NC   16
#define IMG  (256*256)

// LDS map, 40960 B total -> 4 blocks/CU.
//   p   [256 rows][112 B] @ 0      (112 = 16*7: b128 ops are minimal 2-way)
//   w1t [128 rows][ 96 B] @ 28672  (read-only after barrier 1)
// Per-wave bounce aliases the wave's OWN p chunk (7168 B) after barrier 2:
//   h  [16 px][272 B] = 4352 @ +0 ; dx(bf16) [64 px][40 B] = 2560 @ +4352
//   total 6912 <= 7168 -> never touches live w1t.
#define P_STRIDE  112
#define W1_OFF    28672
#define W1_STRIDE 96
#define LDS_TOT   40960
#define CHUNK     7168
#define DX_OFF    4352

static __device__ __forceinline__ unsigned short f2bf(float f) {
    union { __hip_bfloat16 h; unsigned short u; } cv;
    cv.h = __float2bfloat16(f);
    return cv.u;
}
static __device__ __forceinline__ unsigned int packbf2(float a, float b) {
    return (unsigned int)f2bf(a) | ((unsigned int)f2bf(b) << 16);
}
static __device__ __forceinline__ float bflo(unsigned int u) {
    union { unsigned int i; float f; } c; c.i = u << 16; return c.f;
}
static __device__ __forceinline__ float bfhi(unsigned int u) {
    union { unsigned int i; float f; } c; c.i = u & 0xffff0000u; return c.f;
}
static __device__ __forceinline__ f32x4 mfma_bf16_16x16x16(bf16x4 a, bf16x4 b, f32x4 c) {
#if __has_builtin(__builtin_amdgcn_mfma_f32_16x16x16bf16_1k)
    return __builtin_amdgcn_mfma_f32_16x16x16bf16_1k(a, b, c, 0, 0, 0);
#else
    f32x4 d;
    asm("v_mfma_f32_16x16x16_bf16 %0, %1, %2, %3" : "=v"(d) : "v"(a), "v"(b), "v"(c));
    return d;
#endif
}

// ---------------------------------------------------------------------------
// Pass 1: perceive (fp32, double-buffered loads) -> swapped-operand MFMA MLP
// (GEMM1: mfma(w1t, p), K=48=32+16; GEMM2: mfma(w2t, h), K=128) -> per-thread
// epilogue with own-register fire/life bits. Two barriers (round-3 skeleton).
// ---------------------------------------------------------------------------
__global__ __launch_bounds__(256, 4) void nca_update_mfma(
    const float* __restrict__ x, const float* __restrict__ rand_vals,
    const float* __restrict__ w1, const float* __restrict__ b1,
    const float* __restrict__ w2, const float* __restrict__ b2,
    float* __restrict__ out, float* __restrict__ alpha_ws)
{
    __shared__ __align__(16) unsigned char lds[LDS_TOT];
    const int t   = threadIdx.x;
    const int l15 = t & 15, lg = (t >> 4) & 3, wv = t >> 6;

    // XCD-bijective swizzle (4096 = 8 x 512): halo rows share an XCD L2.
    const int wg = (blockIdx.x & 7) * 512 + (blockIdx.x >> 3);
    const int b  = wg >> 8;
    const int h  = wg & 255;
    const int w  = t;

    // ---- w1t staging [n][k], conflict-free: 16 lanes write 16 consecutive
    // u16 within one row (8 dwords -> 8 distinct banks). Bijective over (n,k).
    #pragma unroll
    for (int i = 0; i < 24; i++) {
        int k = (t & 15) + 16 * (i % 3);
        int n = (t >> 4) + 16 * (i / 3);
        *(unsigned short*)(lds + W1_OFF + n*W1_STRIDE + k*2) = f2bf(w1[k*128 + n]);
    }

    // ---- perceive: 8 channel-pairs, double-buffered global loads ----
    const int hm = (h + 255) & 255, hp = (h + 1) & 255;
    const int wm = (w + 255) & 255, wp = (w + 1) & 255;
    const float* xb = x + (size_t)b * NC * IMG;
    const int r0o = hm*256, r1o = h*256, r2o = hp*256;

    const float rv = rand_vals[b*IMG + r1o + w];

    float buf[2][18];
    unsigned int pk[24];
    float premax = 0.0f;

    #pragma unroll
    for (int cc = 0; cc < 2; cc++) {            // channels 0,1
        const float* xc_ = xb + cc*IMG;
        float* bu = &buf[0][cc*9];
        bu[0]=xc_[r0o+wm]; bu[1]=xc_[r0o+w]; bu[2]=xc_[r0o+wp];
        bu[3]=xc_[r1o+wm]; bu[4]=xc_[r1o+w]; bu[5]=xc_[r1o+wp];
        bu[6]=xc_[r2o+wm]; bu[7]=xc_[r2o+w]; bu[8]=xc_[r2o+wp];
    }
    #pragma unroll
    for (int pr = 0; pr < 8; pr++) {
        if (pr < 7) {                           // prefetch next pair
            #pragma unroll
            for (int cc = 0; cc < 2; cc++) {
                const float* xc_ = xb + ((pr+1)*2 + cc)*IMG;
                float* bu = &buf[(pr+1)&1][cc*9];
                bu[0]=xc_[r0o+wm]; bu[1]=xc_[r0o+w]; bu[2]=xc_[r0o+wp];
                bu[3]=xc_[r1o+wm]; bu[4]=xc_[r1o+w]; bu[5]=xc_[r1o+wp];
                bu[6]=xc_[r2o+wm]; bu[7]=xc_[r2o+w]; bu[8]=xc_[r2o+wp];
            }
        }
        float pv[6];
        #pragma unroll
        for (int cc = 0; cc < 2; cc++) {        // channels 2pr, 2pr+1
            const float* a = &buf[pr&1][cc*9];
            pv[cc*3+0] = a[4];
            pv[cc*3+1] = 0.125f*(a[2]-a[0]) + 0.25f*(a[5]-a[3]) + 0.125f*(a[8]-a[6]);
            pv[cc*3+2] = 0.125f*(a[6]-a[0]) + 0.25f*(a[7]-a[1]) + 0.125f*(a[8]-a[2]);
            if (pr*2 + cc == 3)                 // fused pre_life pool (alpha)
                premax = fmaxf(fmaxf(fmaxf(a[0],a[1]),fmaxf(a[2],a[3])),
                         fmaxf(fmaxf(a[4],a[5]),fmaxf(fmaxf(a[6],a[7]),a[8])));
        }
        pk[pr*3+0] = packbf2(pv[0], pv[1]);
        pk[pr*3+1] = packbf2(pv[2], pv[3]);
        pk[pr*3+2] = packbf2(pv[4], pv[5]);
    }

    {   // stage p row (48 bf16 = 96 B of the 112 B row)
        u32x4* pvv = (u32x4*)(lds + t*P_STRIDE);
        #pragma unroll
        for (int j = 0; j < 6; j++) {
            u32x4 v = {pk[4*j], pk[4*j+1], pk[4*j+2], pk[4*j+3]};
            pvv[j] = v;
        }
    }

    // A2 raw loads (w2t[c][k] fragment), issued pre-barrier to hide latency
    float a2raw[32];
    #pragma unroll
    for (int kt = 0; kt < 4; kt++)
        #pragma unroll
        for (int j = 0; j < 8; j++)
            a2raw[kt*8+j] = w2[(kt*32 + lg*8 + j)*16 + l15];

    __syncthreads();   // barrier 1: p + w1t staging complete

    // ---- preloads (p rows of this wave become dead after barrier 2) ----
    bf16x8 A2[4];
    #pragma unroll
    for (int kt = 0; kt < 4; kt++) {
        bf16x8 v;
        #pragma unroll
        for (int j = 0; j < 8; j++) v[j] = (short)f2bf(a2raw[kt*8+j]);
        A2[kt] = v;
    }
    const f32x4 b2f = *(const f32x4*)(b2 + lg*4);

    bf16x8 Bpa[4]; bf16x4 Bpb[4];
    #pragma unroll
    for (int pt = 0; pt < 4; pt++) {
        const unsigned char* r = lds + (wv*64 + pt*16 + l15)*P_STRIDE;
        Bpa[pt] = *(const bf16x8*)(r + lg*16);
        Bpb[pt] = *(const bf16x4*)(r + 64 + lg*8);
    }

    asm volatile("s_waitcnt lgkmcnt(0)" ::: "memory");
    __builtin_amdgcn_sched_barrier(0);
    __syncthreads();   // barrier 2: all preloads done; bounce regions free

    unsigned char* chunk = lds + wv*CHUNK;     // h @ +0, dx @ +DX_OFF

    #pragma unroll
    for (int pt = 0; pt < 4; pt++) {
        // GEMM1: h[hidden][pixel-tile]; A1 read in-loop (w1t never clobbered)
        f32x4 hacc[8];
        #pragma unroll
        for (int mt = 0; mt < 8; mt++) {
            const unsigned char* wr = lds + W1_OFF + (mt*16 + l15)*W1_STRIDE;
            bf16x8 A1a = *(const bf16x8*)(wr + lg*16);
            bf16x4 A1b = *(const bf16x4*)(wr + 64 + lg*8);
            f32x4 acc = *(const f32x4*)(b1 + mt*16 + lg*4);   // L1-hot
            acc = __builtin_amdgcn_mfma_f32_16x16x32_bf16(A1a, Bpa[pt], acc, 0,0,0);
            acc = mfma_bf16_16x16x16(A1b, Bpb[pt], acc);
            hacc[mt] = acc;
        }
        // WAR: previous iteration's Bh reads must retire before h overwrite
        asm volatile("s_waitcnt lgkmcnt(0)" ::: "memory");
        __builtin_amdgcn_sched_barrier(0);
        #pragma unroll
        for (int mt = 0; mt < 8; mt++) {
            u32x2 hq = {packbf2(fmaxf(hacc[mt][0],0.f), fmaxf(hacc[mt][1],0.f)),
                        packbf2(fmaxf(hacc[mt][2],0.f), fmaxf(hacc[mt][3],0.f))};
            *(u32x2*)(chunk + l15*272 + mt*32 + lg*8) = hq;
        }
        asm volatile("s_waitcnt lgkmcnt(0)" ::: "memory");   // RAW: h
        __builtin_amdgcn_sched_barrier(0);
        // GEMM2: dx[chan][pixel-tile]
        f32x4 acc2 = b2f;
        #pragma unroll
        for (int kt = 0; kt < 4; kt++) {
            bf16x8 Bh = *(const bf16x8*)(chunk + l15*272 + kt*64 + lg*16);
            acc2 = __builtin_amdgcn_mfma_f32_16x16x32_bf16(A2[kt], Bh, acc2, 0,0,0);
        }
        // dx bounce, bf16-packed: pixel row 40 B, lane writes ch lg*4..lg*4+3
        u32x2 dq = {packbf2(acc2[0], acc2[1]), packbf2(acc2[2], acc2[3])};
        *(u32x2*)(chunk + DX_OFF + (pt*16 + l15)*40 + lg*8) = dq;
    }
    asm volatile("s_waitcnt lgkmcnt(0)" ::: "memory");       // RAW: dx
    __builtin_amdgcn_sched_barrier(0);

    // ---- epilogue: thread t owns its own pixel (column w = t) ----
    const unsigned char* myd = chunk + DX_OFF + (t & 63)*40;
    u32x2 q0 = *(const u32x2*)(myd +  0);   // ch 0..3
    u32x2 q1 = *(const u32x2*)(myd +  8);   // ch 4..7
    u32x2 q2 = *(const u32x2*)(myd + 16);   // ch 8..11
    u32x2 q3 = *(const u32x2*)(myd + 24);   // ch 12..15
    float dxv[16];
    dxv[0]=bflo(q0.x); dxv[1]=bfhi(q0.x); dxv[2]=bflo(q0.y); dxv[3]=bfhi(q0.y);
    dxv[4]=bflo(q1.x); dxv[5]=bfhi(q1.x); dxv[6]=bflo(q1.y); dxv[7]=bfhi(q1.y);
    dxv[8]=bflo(q2.x); dxv[9]=bfhi(q2.x); dxv[10]=bflo(q2.y); dxv[11]=bfhi(q2.y);
    dxv[12]=bflo(q3.x); dxv[13]=bfhi(q3.x); dxv[14]=bflo(q3.y); dxv[15]=bfhi(q3.y);

    const float fm    = (rv < 0.5f)     ? 1.0f : 0.0f;
    const float lifep = (premax > 0.1f) ? 1.0f : 0.0f;

    const float* xctr = xb + r1o + w;          // re-read centers (L2-hot)
    const float xa = xctr[3*IMG];
    alpha_ws[b*IMG + r1o + w] = fmaf(dxv[3], fm, xa);

    float* ob = out + (size_t)b*NC*IMG + r1o + w;
    #pragma unroll
    for (int c = 0; c < 16; c++)
        ob[(size_t)c*IMG] = fmaf(dxv[c], fm, xctr[(size_t)c*IMG]) * lifep;
}

// ---------------------------------------------------------------------------
// Pass 2: post_life pool over alpha_new; zero the (rare) dead pixels.
// ---------------------------------------------------------------------------
__global__ __launch_bounds__(256) void nca_postmask(
    const float* __restrict__ alpha_ws, float* __restrict__ out)
{
    const int wg = (blockIdx.x & 7) * 512 + (blockIdx.x >> 3);
    const int b  = wg >> 8;
    const int h  = wg & 255;
    const int w  = threadIdx.x;
    const int hm = (h + 255) & 255, hp = (h + 1) & 255;
    const int wm = (w + 255) & 255, wp = (w + 1) & 255;

    const float* na = alpha_ws + b*IMG;
    const float* n0 = na + hm*256;
    const float* n1 = na + h *256;
    const float* n2 = na + hp*256;
    float post = fmaxf(fmaxf(fmaxf(n0[wm],n0[w]),fmaxf(n0[wp],n1[wm])),
                 fmaxf(fmaxf(n1[w],n1[wp]),fmaxf(fmaxf(n2[wm],n2[w]),n2[wp])));
    if (!(post > 0.1f)) {
        float* ob = out + (size_t)b*NC*IMG + h*256 + w;
        #pragma unroll
        for (int c = 0; c < 16; c++) ob[c*IMG] = 0.0f;
    }
}

extern "C" void kernel_launch(void* const* d_in, const int* in_sizes, int n_in,
                              void* d_out, int out_size, void* d_ws, size_t ws_size,
                              hipStream_t stream) {
    const float* x         = (const float*)d_in[0];
    const float* rand_vals = (const float*)d_in[1];
    const float* w1        = (const float*)d_in[2];
    const float* b1        = (const float*)d_in[3];
    const float* w2        = (const float*)d_in[4];
    const float* b2        = (const float*)d_in[5];
    float* out      = (float*)d_out;
    float* alpha_ws = (float*)d_ws;   // 4 MB

    const int grid = 16 * 256;
    nca_update_mfma<<<grid, 256, 0, stream>>>(x, rand_vals, w1, b1, w2, b2,
                                              out, alpha_ws);
    nca_postmask<<<grid, 256, 0, stream>>>(alpha_ws, out);
}

// Round 8
// 61.806 us; speedup vs baseline: 1.5535x; 1.5535x over previous
//
#include <hip/hip_runtime.h>
#include <hip/hip_bf16.h>

typedef __attribute__((ext_vector_type(8))) short bf16x8;
typedef __attribute__((ext_vector_type(4))) short bf16x4;
typedef __attribute__((ext_vector_type(4))) float f32x4;
typedef __attribute__((ext_vector_type(4))) unsigned int u32x4;
typedef __attribute__((ext_vector_type(2))) unsigned int u32x2;

#define NC   16
#define IMG  (256*256)

// LDS layout — VERBATIM from the round-3 kernel that passed at 62.7 us.
//   p   [256 rows][112 B] @ 0
//   w1t [128 rows][112 B] @ 28672
//   w2t [16 rows][272 B]  @ 43008
//   b1  f32[128] @ 47360 ; b2 f32[16] @ 47872
// Per-wave bounce (aliases p/w1t AFTER all fragments preloaded to registers
// and barrier 2): h [16][272 B] @ wv*9472 ; dx f32 [64][80 B] @ wv*9472+4352.
#define P_STRIDE  112
#define W1_OFF    28672
#define W1_STRIDE 112
#define W2_OFF    43008
#define B1_OFF    47360
#define B2_OFF    47872
#define LDS_TOT   47936
#define BNC_SZ    9472
#define BNC_DX    4352

static __device__ __forceinline__ unsigned short f2bf(float f) {
    union { __hip_bfloat16 h; unsigned short u; } cv;
    cv.h = __float2bfloat16(f);
    return cv.u;
}
static __device__ __forceinline__ unsigned int packbf2(float a, float b) {
    return (unsigned int)f2bf(a) | ((unsigned int)f2bf(b) << 16);
}
static __device__ __forceinline__ f32x4 mfma_bf16_16x16x16(bf16x4 a, bf16x4 b, f32x4 c) {
#if __has_builtin(__builtin_amdgcn_mfma_f32_16x16x16bf16_1k)
    return __builtin_amdgcn_mfma_f32_16x16x16bf16_1k(a, b, c, 0, 0, 0);
#else
    f32x4 d;
    asm("v_mfma_f32_16x16x16_bf16 %0, %1, %2, %3" : "=v"(d) : "v"(a), "v"(b), "v"(c));
    return d;
#endif
}

// ---------------------------------------------------------------------------
// Pass 1: R3-verified skeleton. Register-only deltas: double-buffered perceive
// loads, centers kept in registers, early rand load, setprio around MFMA.
// ---------------------------------------------------------------------------
__global__ __launch_bounds__(256, 3) void nca_update_mfma(
    const float* __restrict__ x, const float* __restrict__ rand_vals,
    const float* __restrict__ w1, const float* __restrict__ b1,
    const float* __restrict__ w2, const float* __restrict__ b2,
    float* __restrict__ out, float* __restrict__ alpha_ws)
{
    __shared__ __align__(16) unsigned char lds[LDS_TOT];
    const int t = threadIdx.x;

    // XCD-bijective swizzle (4096 = 8 x 512): halo rows share an XCD L2.
    const int wg = (blockIdx.x & 7) * 512 + (blockIdx.x >> 3);
    const int b  = wg >> 8;
    const int h  = wg & 255;
    const int w  = t;

    // ---- stage weights (R3-verbatim mappings) ----
    #pragma unroll
    for (int i = 0; i < 24; i++) {               // w1 (48x128) -> w1t[n][k]
        int idx = i*256 + t;
        int n = idx & 127, k = idx >> 7;
        *(unsigned short*)(lds + W1_OFF + n*W1_STRIDE + k*2) = f2bf(w1[k*128 + n]);
    }
    #pragma unroll
    for (int i = 0; i < 8; i++) {                // w2 (128x16) -> w2t[c][k]
        int idx = i*256 + t;
        int c = idx & 15, k = idx >> 4;
        *(unsigned short*)(lds + W2_OFF + c*272 + k*2) = f2bf(w2[k*16 + c]);
    }
    if (t < 128) *(float*)(lds + B1_OFF + t*4) = b1[t];
    if (t < 16)  *(float*)(lds + B2_OFF + t*4) = b2[t];

    // ---- perceive (fp32, wrap), double-buffered channel pairs ----
    const int hm = (h + 255) & 255, hp = (h + 1) & 255;
    const int wm = (w + 255) & 255, wp = (w + 1) & 255;
    const float* xb = x + (size_t)b * NC * IMG;
    const int r0o = hm*256, r1o = h*256, r2o = hp*256;

    const float rv = rand_vals[b*IMG + r1o + w];   // early issue

    float buf[2][18];
    unsigned int pk[24];
    float xc[16];
    float premax = 0.0f;

    #pragma unroll
    for (int cc = 0; cc < 2; cc++) {             // channels 0,1
        const float* xc_ = xb + cc*IMG;
        float* bu = &buf[0][cc*9];
        bu[0]=xc_[r0o+wm]; bu[1]=xc_[r0o+w]; bu[2]=xc_[r0o+wp];
        bu[3]=xc_[r1o+wm]; bu[4]=xc_[r1o+w]; bu[5]=xc_[r1o+wp];
        bu[6]=xc_[r2o+wm]; bu[7]=xc_[r2o+w]; bu[8]=xc_[r2o+wp];
    }
    #pragma unroll
    for (int pr = 0; pr < 8; pr++) {
        if (pr < 7) {                            // prefetch next pair
            #pragma unroll
            for (int cc = 0; cc < 2; cc++) {
                const float* xc_ = xb + ((pr+1)*2 + cc)*IMG;
                float* bu = &buf[(pr+1)&1][cc*9];
                bu[0]=xc_[r0o+wm]; bu[1]=xc_[r0o+w]; bu[2]=xc_[r0o+wp];
                bu[3]=xc_[r1o+wm]; bu[4]=xc_[r1o+w]; bu[5]=xc_[r1o+wp];
                bu[6]=xc_[r2o+wm]; bu[7]=xc_[r2o+w]; bu[8]=xc_[r2o+wp];
            }
        }
        float pv[6];
        #pragma unroll
        for (int cc = 0; cc < 2; cc++) {         // channels 2pr, 2pr+1
            const float* a = &buf[pr&1][cc*9];
            pv[cc*3+0] = a[4];
            xc[pr*2+cc] = a[4];
            pv[cc*3+1] = 0.125f*(a[2]-a[0]) + 0.25f*(a[5]-a[3]) + 0.125f*(a[8]-a[6]);
            pv[cc*3+2] = 0.125f*(a[6]-a[0]) + 0.25f*(a[7]-a[1]) + 0.125f*(a[8]-a[2]);
            if (pr*2 + cc == 3)                  // fused pre_life pool (alpha)
                premax = fmaxf(fmaxf(fmaxf(a[0],a[1]),fmaxf(a[2],a[3])),
                         fmaxf(fmaxf(a[4],a[5]),fmaxf(fmaxf(a[6],a[7]),a[8])));
        }
        pk[pr*3+0] = packbf2(pv[0], pv[1]);
        pk[pr*3+1] = packbf2(pv[2], pv[3]);
        pk[pr*3+2] = packbf2(pv[4], pv[5]);
    }

    {   // stage p row (48 bf16, 112 B stride) — R3-verbatim
        u32x4* pvv = (u32x4*)(lds + t*P_STRIDE);
        #pragma unroll
        for (int j = 0; j < 6; j++) {
            u32x4 v = {pk[4*j], pk[4*j+1], pk[4*j+2], pk[4*j+3]};
            pvv[j] = v;
        }
    }
    __syncthreads();   // barrier 1: staging complete

    // ---- preload ALL fragments to registers (R3-verbatim) ----
    const int wv = t >> 6, l15 = t & 15, lg = (t >> 4) & 3;

    bf16x8 A1a[8]; bf16x4 A1b[8];                // w1t rows (hidden-major)
    #pragma unroll
    for (int mt = 0; mt < 8; mt++) {
        const unsigned char* r = lds + W1_OFF + (mt*16 + l15)*W1_STRIDE;
        A1a[mt] = *(const bf16x8*)(r + lg*16);
        A1b[mt] = *(const bf16x4*)(r + 64 + lg*8);
    }
    bf16x8 Bpa[4]; bf16x4 Bpb[4];                // p cols (pixel-major)
    #pragma unroll
    for (int pt = 0; pt < 4; pt++) {
        const unsigned char* r = lds + (wv*64 + pt*16 + l15)*P_STRIDE;
        Bpa[pt] = *(const bf16x8*)(r + lg*16);
        Bpb[pt] = *(const bf16x4*)(r + 64 + lg*8);
    }
    bf16x8 A2[4];                                // w2t rows (channel-major)
    #pragma unroll
    for (int kt = 0; kt < 4; kt++)
        A2[kt] = *(const bf16x8*)(lds + W2_OFF + l15*272 + kt*64 + lg*16);
    f32x4 b2frag = *(const f32x4*)(lds + B2_OFF + lg*16);

    asm volatile("s_waitcnt lgkmcnt(0)" ::: "memory");
    __builtin_amdgcn_sched_barrier(0);
    __syncthreads();   // barrier 2: all preloads done; bounce regions free

    unsigned char* hb  = lds + wv*BNC_SZ;            // h  [16 pix][272 B]
    unsigned char* dxb = lds + wv*BNC_SZ + BNC_DX;   // dx [64 pix][80 B]

    #pragma unroll
    for (int pt = 0; pt < 4; pt++) {
        // GEMM1: h[hidden][pixel-tile], bias from LDS into accumulator
        f32x4 hacc[8];
        __builtin_amdgcn_s_setprio(1);
        #pragma unroll
        for (int mt = 0; mt < 8; mt++) {
            f32x4 a = *(const f32x4*)(lds + B1_OFF + (mt*16 + lg*4)*4);
            a = __builtin_amdgcn_mfma_f32_16x16x32_bf16(A1a[mt], Bpa[pt], a, 0,0,0);
            a = mfma_bf16_16x16x16(A1b[mt], Bpb[pt], a);
            hacc[mt] = a;
        }
        __builtin_amdgcn_s_setprio(0);
        // WAR: previous iteration's Bh reads must retire before h overwrite
        asm volatile("s_waitcnt lgkmcnt(0)" ::: "memory");
        __builtin_amdgcn_sched_barrier(0);
        #pragma unroll
        for (int mt = 0; mt < 8; mt++) {
            u32x2 pk2 = {packbf2(fmaxf(hacc[mt][0],0.f), fmaxf(hacc[mt][1],0.f)),
                         packbf2(fmaxf(hacc[mt][2],0.f), fmaxf(hacc[mt][3],0.f))};
            *(u32x2*)(hb + l15*272 + mt*32 + lg*8) = pk2;
        }
        asm volatile("s_waitcnt lgkmcnt(0)" ::: "memory");   // RAW: h
        __builtin_amdgcn_sched_barrier(0);
        // GEMM2: dx[chan][pixel-tile]
        f32x4 acc2 = b2frag;
        __builtin_amdgcn_s_setprio(1);
        #pragma unroll
        for (int kt = 0; kt < 4; kt++) {
            bf16x8 Bh = *(const bf16x8*)(hb + l15*272 + kt*64 + lg*16);
            acc2 = __builtin_amdgcn_mfma_f32_16x16x32_bf16(A2[kt], Bh, acc2, 0,0,0);
        }
        __builtin_amdgcn_s_setprio(0);
        // lane (l15,lg) holds dx[c=4lg+r][pixel=pt*16+l15] -> one b128
        *(f32x4*)(dxb + (pt*16 + l15)*80 + lg*16) = acc2;
    }
    asm volatile("s_waitcnt lgkmcnt(0)" ::: "memory");       // RAW: dx
    __builtin_amdgcn_sched_barrier(0);

    // ---- epilogue: thread t owns wave-local pixel (t&63) = column w=t ----
    const unsigned char* myd = lds + wv*BNC_SZ + BNC_DX + (t & 63)*80;
    float dxv[16];
    *(f32x4*)&dxv[0]  = *(const f32x4*)(myd +  0);
    *(f32x4*)&dxv[4]  = *(const f32x4*)(myd + 16);
    *(f32x4*)&dxv[8]  = *(const f32x4*)(myd + 32);
    *(f32x4*)&dxv[12] = *(const f32x4*)(myd + 48);

    const float fm    = (rv < 0.5f)     ? 1.0f : 0.0f;
    const float lifep = (premax > 0.1f) ? 1.0f : 0.0f;

    alpha_ws[b*IMG + r1o + w] = fmaf(dxv[3], fm, xc[3]);

    float* ob = out + (size_t)b*NC*IMG + r1o + w;
    #pragma unroll
    for (int c = 0; c < 16; c++)
        ob[(size_t)c*IMG] = fmaf(dxv[c], fm, xc[c]) * lifep;
}

// ---------------------------------------------------------------------------
// Pass 2: post_life pool over alpha_new; zero the (rare) dead pixels.
// ---------------------------------------------------------------------------
__global__ __launch_bounds__(256) void nca_postmask(
    const float* __restrict__ alpha_ws, float* __restrict__ out)
{
    const int wg = (blockIdx.x & 7) * 512 + (blockIdx.x >> 3);
    const int b  = wg >> 8;
    const int h  = wg & 255;
    const int w  = threadIdx.x;
    const int hm = (h + 255) & 255, hp = (h + 1) & 255;
    const int wm = (w + 255) & 255, wp = (w + 1) & 255;

    const float* na = alpha_ws + b*IMG;
    const float* n0 = na + hm*256;
    const float* n1 = na + h *256;
    const float* n2 = na + hp*256;
    float post = fmaxf(fmaxf(fmaxf(n0[wm],n0[w]),fmaxf(n0[wp],n1[wm])),
                 fmaxf(fmaxf(n1[w],n1[wp]),fmaxf(fmaxf(n2[wm],n2[w]),n2[wp])));
    if (!(post > 0.1f)) {
        float* ob = out + (size_t)b*NC*IMG + h*256 + w;
        #pragma unroll
        for (int c = 0; c < 16; c++) ob[c*IMG] = 0.0f;
    }
}

extern "C" void kernel_launch(void* const* d_in, const int* in_sizes, int n_in,
                              void* d_out, int out_size, void* d_ws, size_t ws_size,
                              hipStream_t stream) {
    const float* x         = (const float*)d_in[0];
    const float* rand_vals = (const float*)d_in[1];
    const float* w1        = (const float*)d_in[2];
    const float* b1        = (const float*)d_in[3];
    const float* w2        = (const float*)d_in[4];
    const float* b2        = (const float*)d_in[5];
    float* out      = (float*)d_out;
    float* alpha_ws = (float*)d_ws;   // 4 MB

    const int grid = 16 * 256;
    nca_update_mfma<<<grid, 256, 0, stream>>>(x, rand_vals, w1, b1, w2, b2,
                                              out, alpha_ws);
    nca_postmask<<<grid, 256, 0, stream>>>(alpha_ws, out);
}